// Round 1
// 699.406 us; speedup vs baseline: 1.0209x; 1.0209x over previous
//
#include <hip/hip_runtime.h>
#include <math.h>

// Problem constants (from reference): B=16, T=64, H=32, W=32, C=64
constexpr int Bc = 16, Tc = 64, Hc = 32, Wc = 32, Cc = 64;
constexpr int HWC = Hc * Wc * Cc;              // 65536 = 2^16
constexpr long long NELEM = (long long)Bc * Tc * HWC;  // 67,108,864
constexpr float DECAY_V = 0.8f;
constexpr float VTH_BASE = 0.5f;

typedef float v2f __attribute__((ext_vector_type(2)));

// One thread owns 2 consecutive c-values of one (b,h,w) cell and runs the
// whole T=64 recurrence.
//  - 2 elems/thread (not 4): 524,288 threads = 2048 blocks = exactly
//    8 blocks/CU = 32 waves/CU (max occupancy) vs 16 waves/CU before.
//    The recurrence loop is latency-bound, not BW-bound (2.4 of 6.3 TB/s),
//    so TLP is the lever. 8 B/lane loads are still fully coalesced
//    (512 B per wave instruction).
//  - explicit 1-deep register prefetch of x[t+1] + unroll 8 keeps loads
//    in flight across the serial recurrence.
//  - nontemporal loads/stores: all three big tensors are streamed once.
__global__ __launch_bounds__(256) void alif_fwd_kernel(
    const float* __restrict__ x,             // [B,T,H,W,C]
    const float* __restrict__ hp_base_step,  // scalar
    const float* __restrict__ hp_base_decay, // scalar
    const float* __restrict__ step_w_raw,    // [H,W,C]
    const float* __restrict__ decay_w_raw,   // [H,W,C]
    const float* __restrict__ gamma,         // [H,W,C]
    const float* __restrict__ beta,          // [H,W,C]
    float* __restrict__ spikes,              // [B,T,H,W,C]
    float* __restrict__ volts)               // [B,T,H,W,C]
{
    const int tid = blockIdx.x * blockDim.x + threadIdx.x;  // 0 .. 524287
    const int c2  = tid << 1;              // element index into [B,H,W,C]
    const int b   = c2 >> 16;              // / HWC
    const int hwc = c2 & (HWC - 1);        // % HWC

    const float base_step  = *hp_base_step;   // wave-uniform scalar loads
    const float base_decay = *hp_base_decay;

    const v2f swr = *(const v2f*)(step_w_raw  + hwc);
    const v2f dwr = *(const v2f*)(decay_w_raw + hwc);
    const v2f gm2 = *(const v2f*)(gamma       + hwc);
    const v2f bt2 = *(const v2f*)(beta        + hwc);

    float gm[2]    = {gm2.x, gm2.y};
    float bt[2]    = {bt2.x, bt2.y};
    float swr_a[2] = {swr.x, swr.y};
    float dwr_a[2] = {dwr.x, dwr.y};

    float step_eff[2], decay_eff[2];
    float v[2]   = {0.f, 0.f};
    float vth[2] = {0.f, 0.f};

#pragma unroll
    for (int j = 0; j < 2; ++j) {
        // softplus / sigmoid in double, rounded to f32 -> correctly-rounded
        // f32 param path (matches numpy f32 to within its own exp() ulp).
        float sw = (float)log1p(exp((double)swr_a[j]));
        float dw = (float)(1.0 / (1.0 + exp(-(double)dwr_a[j])));
        step_eff[j]  = base_step * sw;
        decay_eff[j] = base_decay + (1.0f - base_decay) * dw;
    }

    const size_t base = (size_t)b * Tc * HWC + (size_t)hwc;
    const float* xp = x      + base;
    float*       sp = spikes + base;
    float*       vp = volts  + base;

    // software pipeline: x[t+1] load is always in flight during step t
    v2f xcur = __builtin_nontemporal_load((const v2f*)xp);

#pragma unroll 8
    for (int t = 0; t < Tc; ++t) {
        // branch-free prefetch address (clamped so t=63 re-reads row 63
        // instead of running off the buffer); load issued before compute.
        const float* xnp = xp + ((t + 1 < Tc) ? HWC : 0);
        v2f xnext = __builtin_nontemporal_load((const v2f*)xnp);

        float xin[2] = {xcur.x, xcur.y};
        float sarr[2], varr[2];
#pragma unroll
        for (int j = 0; j < 2; ++j) {
            float vv      = v[j] * DECAY_V + (xin[j] * gm[j] + bt[j]);
            float vth_eff = VTH_BASE + vth[j];
            float s       = (vv - vth_eff > 0.0f) ? 1.0f : 0.0f;
            varr[j] = vv;                       // voltage BEFORE reset
            v[j]    = vv - vth_eff * s;         // soft reset
            vth[j]  = vth[j] * decay_eff[j] + s * step_eff[j];
            sarr[j] = s;
        }
        v2f so = {sarr[0], sarr[1]};
        v2f vo = {varr[0], varr[1]};
        __builtin_nontemporal_store(so, (v2f*)sp);
        __builtin_nontemporal_store(vo, (v2f*)vp);

        xcur = xnext;
        xp = xnp; sp += HWC; vp += HWC;
    }
}

extern "C" void kernel_launch(void* const* d_in, const int* in_sizes, int n_in,
                              void* d_out, int out_size, void* d_ws, size_t ws_size,
                              hipStream_t stream) {
    // Input order per setup_inputs():
    // 0: x, 1: hp_alpha (unused in fwd), 2: hp_base_step, 3: hp_base_decay,
    // 4: step_w_raw, 5: decay_w_raw, 6: gamma, 7: beta
    const float* x             = (const float*)d_in[0];
    const float* hp_base_step  = (const float*)d_in[2];
    const float* hp_base_decay = (const float*)d_in[3];
    const float* step_w_raw    = (const float*)d_in[4];
    const float* decay_w_raw   = (const float*)d_in[5];
    const float* gamma         = (const float*)d_in[6];
    const float* beta          = (const float*)d_in[7];

    float* spikes = (float*)d_out;           // output 0: [B,T,H,W,C]
    float* volts  = spikes + NELEM;          // output 1: [B,T,H,W,C]

    const int threads = 256;
    const int total   = Bc * HWC / 2;        // 524,288 threads
    const int blocks  = total / threads;     // 2048 blocks -> 8 blocks/CU

    alif_fwd_kernel<<<blocks, threads, 0, stream>>>(
        x, hp_base_step, hp_base_decay, step_w_raw, decay_w_raw,
        gamma, beta, spikes, volts);
}